// Round 1
// baseline (1358.122 us; speedup 1.0000x reference)
//
#include <hip/hip_runtime.h>

#define NN 100000
#define NE 600000
#define NG 64
#define FD 128

// ---------------- init / degree / CSR build ----------------

__global__ void k_init(int* starts, int* ends, float* psum) {
  int i = blockIdx.x * 256 + threadIdx.x;
  if (i < NG) { starts[i] = NN; ends[i] = 0; }
  if (i < NG * FD) psum[i] = 0.f;
}

__global__ void k_count(const int* __restrict__ col, int* __restrict__ counts) {
  int e = blockIdx.x * 256 + threadIdx.x;
  if (e < NE) atomicAdd(&counts[col[e]], 1);
}

__global__ void k_dinv(const int* __restrict__ counts, float* __restrict__ dinv) {
  int n = blockIdx.x * 256 + threadIdx.x;
  if (n < NN) dinv[n] = rsqrtf((float)counts[n] + 1.0f);
}

// single-block exclusive scan: indptr[0]=0, indptr[i+1]=sum(counts[0..i])
__global__ void k_scan(const int* __restrict__ counts, int* __restrict__ indptr) {
  __shared__ int wsum[16];
  int t = threadIdx.x, lane = t & 63, wid = t >> 6;
  if (t == 0) indptr[0] = 0;
  int carry = 0;
  for (int base = 0; base < NN; base += 1024) {
    int i = base + t;
    int x = (i < NN) ? counts[i] : 0;
#pragma unroll
    for (int d = 1; d < 64; d <<= 1) { int y = __shfl_up(x, d); if (lane >= d) x += y; }
    if (lane == 63) wsum[wid] = x;
    __syncthreads();
    if (wid == 0) {
      int s = (lane < 16) ? wsum[lane] : 0;
#pragma unroll
      for (int d = 1; d < 16; d <<= 1) { int y = __shfl_up(s, d); if (lane >= d) s += y; }
      if (lane < 16) wsum[lane] = s;
    }
    __syncthreads();
    int woff = (wid == 0) ? 0 : wsum[wid - 1];
    if (i < NN) indptr[i + 1] = carry + woff + x;
    carry += wsum[15];
    __syncthreads();
  }
}

__global__ void k_fill(const int* __restrict__ row, const int* __restrict__ col,
                       const int* __restrict__ indptr, int* __restrict__ cursor,
                       const float* __restrict__ dinv,
                       int* __restrict__ srcs, float* __restrict__ nrms) {
  int e = blockIdx.x * 256 + threadIdx.x;
  if (e >= NE) return;
  int c = col[e], r = row[e];
  int p = indptr[c] + atomicAdd(&cursor[c], 1);
  srcs[p] = r;
  nrms[p] = dinv[r] * dinv[c];
}

__global__ void k_bounds(const int* __restrict__ batch, int* starts, int* ends) {
  int n = blockIdx.x * 256 + threadIdx.x;
  if (n < NN) {
    int g = batch[n];
    atomicMin(&starts[g], n);
    atomicMax(&ends[g], n + 1);
  }
}

// ---------------- GEMM: H[M,128] = A[M,128] @ W[128,128] ----------------
// block 256 threads, 64 rows per block, K chunked by 32.
#define BM 64
#define BKC 32

__global__ __launch_bounds__(256) void k_gemm(const float* __restrict__ A,
                                              const float* __restrict__ W,
                                              float* __restrict__ H, int M) {
  __shared__ float xs[BM][BKC + 1];   // 64 x 33 floats (pad breaks stride)
  __shared__ float wsh[BKC][FD];      // 32 x 128 floats
  int t = threadIdx.x;
  int tc = t & 31;        // col group: cols tc*4 .. tc*4+3
  int tr = t >> 5;        // row group: rows tr*8 .. tr*8+7
  int rowBase = blockIdx.x * BM;
  float acc[8][4] = {{0.f}};

  for (int k0 = 0; k0 < FD; k0 += BKC) {
    // stage A tile: 64 rows x 32 k
    int lr = t >> 3;            // 0..31
    int lk = (t & 7) * 4;       // 0..28
#pragma unroll
    for (int rr = 0; rr < BM; rr += 32) {
      int gr = rowBase + lr + rr;
      int gsrc = gr < M ? gr : (M - 1);
      float4 v = *(const float4*)&A[(size_t)gsrc * FD + k0 + lk];
      xs[lr + rr][lk + 0] = v.x;
      xs[lr + rr][lk + 1] = v.y;
      xs[lr + rr][lk + 2] = v.z;
      xs[lr + rr][lk + 3] = v.w;
    }
    // stage W chunk: 32 k x 128 cols
#pragma unroll
    for (int j = 0; j < 4; ++j) {
      int fi = t + j * 256;           // float4 index, 0..1023
      int kk = fi >> 5;               // 0..31
      int c = (fi & 31) * 4;          // 0..124
      float4 v = *(const float4*)&W[(size_t)(k0 + kk) * FD + c];
      *(float4*)&wsh[kk][c] = v;
    }
    __syncthreads();
#pragma unroll
    for (int kk = 0; kk < BKC; ++kk) {
      float4 b = *(const float4*)&wsh[kk][tc * 4];
      float a[8];
#pragma unroll
      for (int i = 0; i < 8; ++i) a[i] = xs[tr * 8 + i][kk];
#pragma unroll
      for (int i = 0; i < 8; ++i) {
        acc[i][0] += a[i] * b.x;
        acc[i][1] += a[i] * b.y;
        acc[i][2] += a[i] * b.z;
        acc[i][3] += a[i] * b.w;
      }
    }
    __syncthreads();
  }
#pragma unroll
  for (int i = 0; i < 8; ++i) {
    int gr = rowBase + tr * 8 + i;
    if (gr < M) {
      float4 v = make_float4(acc[i][0], acc[i][1], acc[i][2], acc[i][3]);
      *(float4*)&H[(size_t)gr * FD + tc * 4] = v;
    }
  }
}

// ---------------- aggregation: out[n] = sum_e nrm*H[src] + dinv^2*H[n] + b ----------------
__global__ __launch_bounds__(256) void k_agg(const float* __restrict__ H,
                                             const int* __restrict__ indptr,
                                             const int* __restrict__ srcs,
                                             const float* __restrict__ nrms,
                                             const float* __restrict__ dinv,
                                             const float* __restrict__ bias,
                                             float* __restrict__ out, int relu) {
  int n = blockIdx.x * 2 + (threadIdx.x >> 7);
  int f = threadIdx.x & 127;
  if (n >= NN) return;
  float dv = dinv[n];
  float acc = dv * dv * H[(size_t)n * FD + f];
  int e0 = indptr[n], e1 = indptr[n + 1];
  for (int e = e0; e < e1; ++e) {
    acc += nrms[e] * H[(size_t)srcs[e] * FD + f];
  }
  acc += bias[f];
  if (relu) acc = fmaxf(acc, 0.f);
  out[(size_t)n * FD + f] = acc;
}

// ---------------- mean pool (batch is sorted -> contiguous ranges) ----------------
__global__ void k_pool(const float* __restrict__ H, const int* __restrict__ starts,
                       const int* __restrict__ ends, float* __restrict__ psum) {
  int g = blockIdx.x >> 3;
  int s = blockIdx.x & 7;
  int f = threadIdx.x;  // 128
  int n0 = starts[g], n1 = ends[g];
  if (n1 <= n0) return;
  long long len = n1 - n0;
  int a = n0 + (int)(len * s / 8);
  int b = n0 + (int)(len * (s + 1) / 8);
  float acc = 0.f;
  for (int n = a; n < b; ++n) acc += H[(size_t)n * FD + f];
  atomicAdd(&psum[g * FD + f], acc);
}

__global__ void k_head(const float* __restrict__ psum, const int* __restrict__ starts,
                       const int* __restrict__ ends, const float* __restrict__ Wl,
                       const float* __restrict__ bl, float* __restrict__ out) {
  int t = threadIdx.x;  // 128 = 64 graphs x 2 classes
  int g = t >> 1, c = t & 1;
  int cnt = ends[g] - starts[g];
  if (cnt < 0) cnt = 0;
  float inv = 1.f / (float)(cnt > 0 ? cnt : 1);
  float acc = 0.f;
  for (int k = 0; k < FD; ++k) acc += psum[g * FD + k] * Wl[k * 2 + c];
  out[g * 2 + c] = acc * inv + bl[c];
}

// ---------------- host ----------------

extern "C" void kernel_launch(void* const* d_in, const int* in_sizes, int n_in,
                              void* d_out, int out_size, void* d_ws, size_t ws_size,
                              hipStream_t stream) {
  const float* x  = (const float*)d_in[0];
  const int* ei   = (const int*)d_in[1];    // [2, NE] -> row = ei, col = ei+NE
  const int* bat  = (const int*)d_in[2];
  const float* W1 = (const float*)d_in[3];
  const float* b1 = (const float*)d_in[4];
  const float* W2 = (const float*)d_in[5];
  const float* b2 = (const float*)d_in[6];
  const float* W3 = (const float*)d_in[7];
  const float* b3 = (const float*)d_in[8];
  const float* Wl = (const float*)d_in[9];
  const float* bl = (const float*)d_in[10];
  float* out = (float*)d_out;

  char* ws = (char*)d_ws;
  size_t off = 0;
  auto alloc = [&](size_t bytes) {
    void* p = ws + off;
    off += (bytes + 255) & ~(size_t)255;
    return p;
  };
  int* counts  = (int*)alloc(NN * 4);
  int* cursor  = (int*)alloc(NN * 4);
  int* indptr  = (int*)alloc((NN + 1) * 4);
  float* dinv  = (float*)alloc(NN * 4);
  int* starts  = (int*)alloc(NG * 4);
  int* ends    = (int*)alloc(NG * 4);
  float* psum  = (float*)alloc(NG * FD * 4);
  int* srcs    = (int*)alloc(NE * 4);
  float* nrms  = (float*)alloc(NE * 4);
  float* bufH  = (float*)alloc((size_t)NN * FD * 4);
  float* bufA  = (float*)alloc((size_t)NN * FD * 4);

  const int* row = ei;
  const int* col = ei + NE;

  hipMemsetAsync(counts, 0, NN * 4, stream);
  hipMemsetAsync(cursor, 0, NN * 4, stream);
  k_init<<<32, 256, 0, stream>>>(starts, ends, psum);
  k_bounds<<<(NN + 255) / 256, 256, 0, stream>>>(bat, starts, ends);
  k_count<<<(NE + 255) / 256, 256, 0, stream>>>(col, counts);
  k_dinv<<<(NN + 255) / 256, 256, 0, stream>>>(counts, dinv);
  k_scan<<<1, 1024, 0, stream>>>(counts, indptr);
  k_fill<<<(NE + 255) / 256, 256, 0, stream>>>(row, col, indptr, cursor, dinv, srcs, nrms);

  int gemmGrid = (NN + BM - 1) / BM;
  int aggGrid = (NN + 1) / 2;

  // layer 1: relu(agg(x @ W1) + b1)
  k_gemm<<<gemmGrid, 256, 0, stream>>>(x, W1, bufH, NN);
  k_agg<<<aggGrid, 256, 0, stream>>>(bufH, indptr, srcs, nrms, dinv, b1, bufA, 1);
  // layer 2
  k_gemm<<<gemmGrid, 256, 0, stream>>>(bufA, W2, bufH, NN);
  k_agg<<<aggGrid, 256, 0, stream>>>(bufH, indptr, srcs, nrms, dinv, b2, bufA, 1);
  // layer 3 (no relu)
  k_gemm<<<gemmGrid, 256, 0, stream>>>(bufA, W3, bufH, NN);
  k_agg<<<aggGrid, 256, 0, stream>>>(bufH, indptr, srcs, nrms, dinv, b3, bufA, 0);

  k_pool<<<NG * 8, 128, 0, stream>>>(bufA, starts, ends, psum);
  k_head<<<1, 128, 0, stream>>>(psum, starts, ends, Wl, bl, out);
}

// Round 2
// 755.144 us; speedup vs baseline: 1.7985x; 1.7985x over previous
//
#include <hip/hip_runtime.h>

#define NN 100000
#define NE 600000
#define NG 64
#define FD 128

// ---------------- init / degree / CSR build ----------------

__global__ void k_init(float* psum) {
  int i = blockIdx.x * 256 + threadIdx.x;
  if (i < NG * FD) psum[i] = 0.f;
}

__global__ void k_count(const int* __restrict__ col, int* __restrict__ counts) {
  int e = blockIdx.x * 256 + threadIdx.x;
  if (e < NE) atomicAdd(&counts[col[e]], 1);
}

__global__ void k_dinv(const int* __restrict__ counts, float* __restrict__ dinv) {
  int n = blockIdx.x * 256 + threadIdx.x;
  if (n < NN) dinv[n] = rsqrtf((float)counts[n] + 1.0f);
}

// single-block exclusive scan: indptr[0]=0, indptr[i+1]=sum(counts[0..i])
__global__ void k_scan(const int* __restrict__ counts, int* __restrict__ indptr) {
  __shared__ int wsum[16];
  int t = threadIdx.x, lane = t & 63, wid = t >> 6;
  if (t == 0) indptr[0] = 0;
  int carry = 0;
  for (int base = 0; base < NN; base += 1024) {
    int i = base + t;
    int x = (i < NN) ? counts[i] : 0;
#pragma unroll
    for (int d = 1; d < 64; d <<= 1) { int y = __shfl_up(x, d); if (lane >= d) x += y; }
    if (lane == 63) wsum[wid] = x;
    __syncthreads();
    if (wid == 0) {
      int s = (lane < 16) ? wsum[lane] : 0;
#pragma unroll
      for (int d = 1; d < 16; d <<= 1) { int y = __shfl_up(s, d); if (lane >= d) s += y; }
      if (lane < 16) wsum[lane] = s;
    }
    __syncthreads();
    int woff = (wid == 0) ? 0 : wsum[wid - 1];
    if (i < NN) indptr[i + 1] = carry + woff + x;
    carry += wsum[15];
    __syncthreads();
  }
}

__global__ void k_fill(const int* __restrict__ row, const int* __restrict__ col,
                       const int* __restrict__ indptr, int* __restrict__ cursor,
                       const float* __restrict__ dinv,
                       int* __restrict__ srcs, float* __restrict__ nrms) {
  int e = blockIdx.x * 256 + threadIdx.x;
  if (e >= NE) return;
  int c = col[e], r = row[e];
  int p = indptr[c] + atomicAdd(&cursor[c], 1);
  srcs[p] = r;
  nrms[p] = dinv[r] * dinv[c];
}

// batch is sorted: find graph ranges by boundary detection, no atomics.
__global__ void k_ranges(const int* __restrict__ batch, int* __restrict__ starts,
                         int* __restrict__ ends) {
  int n = blockIdx.x * 256 + threadIdx.x;
  if (n >= NN) return;
  int g = batch[n];
  if (n == 0) {
    starts[g] = 0;
    for (int q = 0; q < g; ++q) { starts[q] = 0; ends[q] = 0; }
  } else {
    int gp = batch[n - 1];
    if (gp != g) {
      ends[gp] = n;
      starts[g] = n;
      for (int q = gp + 1; q < g; ++q) { starts[q] = n; ends[q] = n; }
    }
  }
  if (n == NN - 1) {
    ends[g] = NN;
    for (int q = g + 1; q < NG; ++q) { starts[q] = NN; ends[q] = NN; }
  }
}

// ---------------- GEMM: H[M,128] = A[M,128] @ W[128,128] ----------------
// block 256 threads, 64 rows per block, K chunked by 32.
#define BM 64
#define BKC 32

__global__ __launch_bounds__(256) void k_gemm(const float* __restrict__ A,
                                              const float* __restrict__ W,
                                              float* __restrict__ H, int M) {
  __shared__ float xs[BM][BKC + 1];   // pad breaks stride
  __shared__ float wsh[BKC][FD];
  int t = threadIdx.x;
  int tc = t & 31;        // col group: cols tc*4 .. tc*4+3
  int tr = t >> 5;        // row group: rows tr*8 .. tr*8+7
  int rowBase = blockIdx.x * BM;
  float acc[8][4] = {{0.f}};

  for (int k0 = 0; k0 < FD; k0 += BKC) {
    int lr = t >> 3;            // 0..31
    int lk = (t & 7) * 4;       // 0..28
#pragma unroll
    for (int rr = 0; rr < BM; rr += 32) {
      int gr = rowBase + lr + rr;
      int gsrc = gr < M ? gr : (M - 1);
      float4 v = *(const float4*)&A[(size_t)gsrc * FD + k0 + lk];
      xs[lr + rr][lk + 0] = v.x;
      xs[lr + rr][lk + 1] = v.y;
      xs[lr + rr][lk + 2] = v.z;
      xs[lr + rr][lk + 3] = v.w;
    }
#pragma unroll
    for (int j = 0; j < 4; ++j) {
      int fi = t + j * 256;
      int kk = fi >> 5;
      int c = (fi & 31) * 4;
      float4 v = *(const float4*)&W[(size_t)(k0 + kk) * FD + c];
      *(float4*)&wsh[kk][c] = v;
    }
    __syncthreads();
#pragma unroll
    for (int kk = 0; kk < BKC; ++kk) {
      float4 b = *(const float4*)&wsh[kk][tc * 4];
      float a[8];
#pragma unroll
      for (int i = 0; i < 8; ++i) a[i] = xs[tr * 8 + i][kk];
#pragma unroll
      for (int i = 0; i < 8; ++i) {
        acc[i][0] += a[i] * b.x;
        acc[i][1] += a[i] * b.y;
        acc[i][2] += a[i] * b.z;
        acc[i][3] += a[i] * b.w;
      }
    }
    __syncthreads();
  }
#pragma unroll
  for (int i = 0; i < 8; ++i) {
    int gr = rowBase + tr * 8 + i;
    if (gr < M) {
      float4 v = make_float4(acc[i][0], acc[i][1], acc[i][2], acc[i][3]);
      *(float4*)&H[(size_t)gr * FD + tc * 4] = v;
    }
  }
}

// ---------------- aggregation ----------------
__global__ __launch_bounds__(256) void k_agg(const float* __restrict__ H,
                                             const int* __restrict__ indptr,
                                             const int* __restrict__ srcs,
                                             const float* __restrict__ nrms,
                                             const float* __restrict__ dinv,
                                             const float* __restrict__ bias,
                                             float* __restrict__ out, int relu) {
  int n = blockIdx.x * 2 + (threadIdx.x >> 7);
  int f = threadIdx.x & 127;
  if (n >= NN) return;
  float dv = dinv[n];
  float acc = dv * dv * H[(size_t)n * FD + f];
  int e0 = indptr[n], e1 = indptr[n + 1];
  for (int e = e0; e < e1; ++e) {
    acc += nrms[e] * H[(size_t)srcs[e] * FD + f];
  }
  acc += bias[f];
  if (relu) acc = fmaxf(acc, 0.f);
  out[(size_t)n * FD + f] = acc;
}

// ---------------- mean pool (contiguous per-graph ranges) ----------------
__global__ void k_pool(const float* __restrict__ H, const int* __restrict__ starts,
                       const int* __restrict__ ends, float* __restrict__ psum) {
  int g = blockIdx.x >> 3;
  int s = blockIdx.x & 7;
  int f = threadIdx.x;  // 128
  int n0 = starts[g], n1 = ends[g];
  if (n1 <= n0) return;
  long long len = n1 - n0;
  int a = n0 + (int)(len * s / 8);
  int b = n0 + (int)(len * (s + 1) / 8);
  float acc = 0.f;
  for (int n = a; n < b; ++n) acc += H[(size_t)n * FD + f];
  atomicAdd(&psum[g * FD + f], acc);
}

__global__ void k_head(const float* __restrict__ psum, const int* __restrict__ starts,
                       const int* __restrict__ ends, const float* __restrict__ Wl,
                       const float* __restrict__ bl, float* __restrict__ out) {
  int t = threadIdx.x;  // 128 = 64 graphs x 2 classes
  int g = t >> 1, c = t & 1;
  int cnt = ends[g] - starts[g];
  if (cnt < 0) cnt = 0;
  float inv = 1.f / (float)(cnt > 0 ? cnt : 1);
  float acc = 0.f;
  for (int k = 0; k < FD; ++k) acc += psum[g * FD + k] * Wl[k * 2 + c];
  out[g * 2 + c] = acc * inv + bl[c];
}

// ---------------- host ----------------

extern "C" void kernel_launch(void* const* d_in, const int* in_sizes, int n_in,
                              void* d_out, int out_size, void* d_ws, size_t ws_size,
                              hipStream_t stream) {
  const float* x  = (const float*)d_in[0];
  const int* ei   = (const int*)d_in[1];    // [2, NE] -> row = ei, col = ei+NE
  const int* bat  = (const int*)d_in[2];
  const float* W1 = (const float*)d_in[3];
  const float* b1 = (const float*)d_in[4];
  const float* W2 = (const float*)d_in[5];
  const float* b2 = (const float*)d_in[6];
  const float* W3 = (const float*)d_in[7];
  const float* b3 = (const float*)d_in[8];
  const float* Wl = (const float*)d_in[9];
  const float* bl = (const float*)d_in[10];
  float* out = (float*)d_out;

  char* ws = (char*)d_ws;
  size_t off = 0;
  auto alloc = [&](size_t bytes) {
    void* p = ws + off;
    off += (bytes + 255) & ~(size_t)255;
    return p;
  };
  int* counts  = (int*)alloc(NN * 4);
  int* cursor  = (int*)alloc(NN * 4);
  int* indptr  = (int*)alloc((NN + 1) * 4);
  float* dinv  = (float*)alloc(NN * 4);
  int* starts  = (int*)alloc(NG * 4);
  int* ends    = (int*)alloc(NG * 4);
  float* psum  = (float*)alloc(NG * FD * 4);
  int* srcs    = (int*)alloc(NE * 4);
  float* nrms  = (float*)alloc(NE * 4);
  float* bufH  = (float*)alloc((size_t)NN * FD * 4);
  float* bufA  = (float*)alloc((size_t)NN * FD * 4);

  const int* row = ei;
  const int* col = ei + NE;

  hipMemsetAsync(counts, 0, NN * 4, stream);
  hipMemsetAsync(cursor, 0, NN * 4, stream);
  k_init<<<32, 256, 0, stream>>>(psum);
  k_ranges<<<(NN + 255) / 256, 256, 0, stream>>>(bat, starts, ends);
  k_count<<<(NE + 255) / 256, 256, 0, stream>>>(col, counts);
  k_dinv<<<(NN + 255) / 256, 256, 0, stream>>>(counts, dinv);
  k_scan<<<1, 1024, 0, stream>>>(counts, indptr);
  k_fill<<<(NE + 255) / 256, 256, 0, stream>>>(row, col, indptr, cursor, dinv, srcs, nrms);

  int gemmGrid = (NN + BM - 1) / BM;
  int aggGrid = (NN + 1) / 2;

  // layer 1: relu(agg(x @ W1) + b1)
  k_gemm<<<gemmGrid, 256, 0, stream>>>(x, W1, bufH, NN);
  k_agg<<<aggGrid, 256, 0, stream>>>(bufH, indptr, srcs, nrms, dinv, b1, bufA, 1);
  // layer 2
  k_gemm<<<gemmGrid, 256, 0, stream>>>(bufA, W2, bufH, NN);
  k_agg<<<aggGrid, 256, 0, stream>>>(bufH, indptr, srcs, nrms, dinv, b2, bufA, 1);
  // layer 3 (no relu)
  k_gemm<<<gemmGrid, 256, 0, stream>>>(bufA, W3, bufH, NN);
  k_agg<<<aggGrid, 256, 0, stream>>>(bufH, indptr, srcs, nrms, dinv, b3, bufA, 0);

  k_pool<<<NG * 8, 128, 0, stream>>>(bufA, starts, ends, psum);
  k_head<<<1, 128, 0, stream>>>(psum, starts, ends, Wl, bl, out);
}

// Round 3
// 437.061 us; speedup vs baseline: 3.1074x; 1.7278x over previous
//
#include <hip/hip_runtime.h>

#define NN 100000
#define NE 600000
#define NG 64
#define FD 128
#define NB 98   // scan blocks of 1024: 98*1024 >= NN

typedef __attribute__((ext_vector_type(8))) short s8v;
typedef __attribute__((ext_vector_type(4))) float f4v;

__device__ inline float bflo(unsigned u) { return __uint_as_float(u << 16); }
__device__ inline float bfhi(unsigned u) { return __uint_as_float(u & 0xFFFF0000u); }
__device__ inline unsigned f2bfbits(float f) {  // round-to-nearest-even
  unsigned x = __float_as_uint(f);
  return (x + 0x7FFFu + ((x >> 16) & 1u)) >> 16;
}
__device__ inline unsigned pack2(float a, float b) { return f2bfbits(a) | (f2bfbits(b) << 16); }

// ---------------- casts ----------------

__global__ void k_castx(const float* __restrict__ x, uint2* __restrict__ xb) {
  long long g = blockIdx.x * 256 + threadIdx.x;  // one float4 group
  if (g >= (long long)NN * FD / 4) return;
  float4 v = ((const float4*)x)[g];
  xb[g] = make_uint2(pack2(v.x, v.y), pack2(v.z, v.w));
}

// W f32 [K][N] -> WThi/WTlo bf16 [N][K] (transposed, hi + residual-lo)
__global__ void k_castW(const float* __restrict__ W, unsigned short* __restrict__ WThi,
                        unsigned short* __restrict__ WTlo) {
  int e = blockIdx.x * 256 + threadIdx.x;
  if (e >= FD * FD) return;
  int k = e >> 7, n = e & 127;
  float v = W[e];
  unsigned hb = f2bfbits(v);
  float hf = __uint_as_float(hb << 16);
  unsigned lb = f2bfbits(v - hf);
  WThi[n * FD + k] = (unsigned short)hb;
  WTlo[n * FD + k] = (unsigned short)lb;
}

// ---------------- degree / CSR build ----------------

__global__ void k_init(float* psum) {
  int i = blockIdx.x * 256 + threadIdx.x;
  if (i < NG * FD) psum[i] = 0.f;
}

__global__ void k_count(const int* __restrict__ col, int* __restrict__ counts) {
  int e = blockIdx.x * 256 + threadIdx.x;
  if (e < NE) atomicAdd(&counts[col[e]], 1);
}

__global__ void k_dinv(const int* __restrict__ counts, float* __restrict__ dinv) {
  int n = blockIdx.x * 256 + threadIdx.x;
  if (n < NN) dinv[n] = rsqrtf((float)counts[n] + 1.0f);
}

// 3-phase scan: block sums -> scan of block sums -> per-block scan + offset
__global__ void k_bsum(const int* __restrict__ counts, int* __restrict__ bsum) {
  __shared__ int wsm[16];
  int b = blockIdx.x, t = threadIdx.x;
  int i = b * 1024 + t;
  int x = (i < NN) ? counts[i] : 0;
#pragma unroll
  for (int d = 32; d; d >>= 1) x += __shfl_down(x, d);
  if ((t & 63) == 0) wsm[t >> 6] = x;
  __syncthreads();
  if (t < 16) {
    int s = wsm[t];
#pragma unroll
    for (int d = 8; d; d >>= 1) s += __shfl_down(s, d);
    if (t == 0) bsum[b] = s;
  }
}

__global__ void k_bscan(const int* __restrict__ bsum, int* __restrict__ eb) {
  __shared__ int w0;
  int t = threadIdx.x;  // 128
  int x = (t < NB) ? bsum[t] : 0;
  int lane = t & 63;
  int inc = x;
#pragma unroll
  for (int d = 1; d < 64; d <<= 1) { int y = __shfl_up(inc, d); if (lane >= d) inc += y; }
  if (t == 63) w0 = inc;
  __syncthreads();
  int off = (t >= 64) ? w0 : 0;
  if (t < NB) eb[t] = off + inc - x;  // exclusive
}

__global__ void k_scan2(const int* __restrict__ counts, const int* __restrict__ eb,
                        int* __restrict__ indptr) {
  __shared__ int wsm[16];
  int b = blockIdx.x, t = threadIdx.x;
  int i = b * 1024 + t;
  int x = (i < NN) ? counts[i] : 0;
  int lane = t & 63, wid = t >> 6;
  int inc = x;
#pragma unroll
  for (int d = 1; d < 64; d <<= 1) { int y = __shfl_up(inc, d); if (lane >= d) inc += y; }
  if (lane == 63) wsm[wid] = inc;
  __syncthreads();
  if (wid == 0) {
    int s = (lane < 16) ? wsm[lane] : 0;
#pragma unroll
    for (int d = 1; d < 16; d <<= 1) { int y = __shfl_up(s, d); if (lane >= d) s += y; }
    if (lane < 16) wsm[lane] = s;
  }
  __syncthreads();
  int woff = wid ? wsm[wid - 1] : 0;
  if (i < NN) indptr[i + 1] = eb[b] + woff + inc;
  if (i == 0) indptr[0] = 0;
}

__global__ void k_fill(const int* __restrict__ row, const int* __restrict__ col,
                       const int* __restrict__ indptr, int* __restrict__ cursor,
                       const float* __restrict__ dinv,
                       int* __restrict__ srcs, float* __restrict__ nrms) {
  int e = blockIdx.x * 256 + threadIdx.x;
  if (e >= NE) return;
  int c = col[e], r = row[e];
  int p = indptr[c] + atomicAdd(&cursor[c], 1);
  srcs[p] = r;
  nrms[p] = dinv[r] * dinv[c];
}

// batch is sorted: ranges by boundary detection
__global__ void k_ranges(const int* __restrict__ batch, int* __restrict__ starts,
                         int* __restrict__ ends) {
  int n = blockIdx.x * 256 + threadIdx.x;
  if (n >= NN) return;
  int g = batch[n];
  if (n == 0) {
    starts[g] = 0;
    for (int q = 0; q < g; ++q) { starts[q] = 0; ends[q] = 0; }
  } else {
    int gp = batch[n - 1];
    if (gp != g) {
      ends[gp] = n;
      starts[g] = n;
      for (int q = gp + 1; q < g; ++q) { starts[q] = n; ends[q] = n; }
    }
  }
  if (n == NN - 1) {
    ends[g] = NN;
    for (int q = g + 1; q < NG; ++q) { starts[q] = NN; ends[q] = NN; }
  }
}

// ---------------- MFMA GEMM: Hb[M,128] = Ab[M,128] @ (WThi+WTlo)^T ----------------
// 256 threads = 4 waves; 128 rows/block (32 rows/wave = 2 row-tiles of 16).
// W staged in LDS as [n][k], row stride 136 el (272 B = 17*16: aligned + bank-rotated).
__global__ __launch_bounds__(256) void k_gemm(const unsigned short* __restrict__ Ab,
                                              const unsigned short* __restrict__ WThi,
                                              const unsigned short* __restrict__ WTlo,
                                              unsigned short* __restrict__ Hb, int M) {
  __shared__ unsigned short wt[128][136];
  int t = threadIdx.x, lane = t & 63, w = t >> 6;
  int rowBase = blockIdx.x * 128 + w * 32;
  int r16 = lane & 15, kg = lane >> 4;

  f4v acc[2][8];
#pragma unroll
  for (int rt = 0; rt < 2; ++rt)
#pragma unroll
    for (int n = 0; n < 8; ++n) acc[rt][n] = (f4v){0.f, 0.f, 0.f, 0.f};

  // A fragments: lane holds A[row=r16][k = kg*8 + j] per 32-k chunk c
  s8v afr[2][4];
#pragma unroll
  for (int rt = 0; rt < 2; ++rt) {
    int ar = rowBase + rt * 16 + r16;
    if (ar > M - 1) ar = M - 1;
    const unsigned short* ap = Ab + (size_t)ar * FD + kg * 8;
#pragma unroll
    for (int c = 0; c < 4; ++c) afr[rt][c] = *(const s8v*)(ap + c * 32);
  }

  for (int pass = 0; pass < 2; ++pass) {
    const unsigned short* Wg = pass ? WTlo : WThi;
    {  // stage 128x128 bf16 into LDS
      int n = t >> 1, koff = (t & 1) * 64;
      const unsigned short* src = Wg + n * FD + koff;
#pragma unroll
      for (int j = 0; j < 8; ++j)
        *(s8v*)&wt[n][koff + j * 8] = *(const s8v*)(src + j * 8);
    }
    __syncthreads();
#pragma unroll
    for (int n = 0; n < 8; ++n) {
#pragma unroll
      for (int c = 0; c < 4; ++c) {
        s8v bfr = *(const s8v*)&wt[n * 16 + r16][c * 32 + kg * 8];
        acc[0][n] = __builtin_amdgcn_mfma_f32_16x16x32_bf16(afr[0][c], bfr, acc[0][n], 0, 0, 0);
        acc[1][n] = __builtin_amdgcn_mfma_f32_16x16x32_bf16(afr[1][c], bfr, acc[1][n], 0, 0, 0);
      }
    }
    __syncthreads();
  }

  // epilogue: D lane layout col = r16, row = kg*4 + j
#pragma unroll
  for (int rt = 0; rt < 2; ++rt)
#pragma unroll
    for (int j = 0; j < 4; ++j) {
      int r = rowBase + rt * 16 + kg * 4 + j;
      if (r < M) {
#pragma unroll
        for (int n = 0; n < 8; ++n)
          Hb[(size_t)r * FD + n * 16 + r16] = (unsigned short)f2bfbits(acc[rt][n][j]);
      }
    }
}

// ---------------- aggregation: bf16 in/out, f32 accumulate ----------------
// one wave per node; lane covers 2 feats via bf16x2 (uint) loads
__global__ __launch_bounds__(256) void k_agg(const unsigned* __restrict__ H2,
                                             const int* __restrict__ indptr,
                                             const int* __restrict__ srcs,
                                             const float* __restrict__ nrms,
                                             const float* __restrict__ dinv,
                                             const float* __restrict__ bias,
                                             unsigned* __restrict__ out2, int relu) {
  int n = blockIdx.x * 4 + (threadIdx.x >> 6);
  int lane = threadIdx.x & 63;
  if (n >= NN) return;
  float dv = dinv[n];
  float s2 = dv * dv;
  unsigned u = H2[(size_t)n * 64 + lane];
  float a0 = s2 * bflo(u), a1 = s2 * bfhi(u);
  int e0 = indptr[n], e1 = indptr[n + 1];
  for (int e = e0; e < e1; ++e) {
    unsigned v = H2[(size_t)srcs[e] * 64 + lane];
    float wgt = nrms[e];
    a0 += wgt * bflo(v);
    a1 += wgt * bfhi(v);
  }
  a0 += bias[lane * 2];
  a1 += bias[lane * 2 + 1];
  if (relu) { a0 = fmaxf(a0, 0.f); a1 = fmaxf(a1, 0.f); }
  out2[(size_t)n * 64 + lane] = pack2(a0, a1);
}

// ---------------- mean pool (bf16 input) ----------------
__global__ void k_pool(const unsigned short* __restrict__ Ab, const int* __restrict__ starts,
                       const int* __restrict__ ends, float* __restrict__ psum) {
  int g = blockIdx.x >> 3;
  int s = blockIdx.x & 7;
  int f = threadIdx.x;  // 128
  int n0 = starts[g], n1 = ends[g];
  if (n1 <= n0) return;
  long long len = n1 - n0;
  int a = n0 + (int)(len * s / 8);
  int b = n0 + (int)(len * (s + 1) / 8);
  float acc = 0.f;
  for (int n = a; n < b; ++n) acc += __uint_as_float(((unsigned)Ab[(size_t)n * FD + f]) << 16);
  atomicAdd(&psum[g * FD + f], acc);
}

__global__ void k_head(const float* __restrict__ psum, const int* __restrict__ starts,
                       const int* __restrict__ ends, const float* __restrict__ Wl,
                       const float* __restrict__ bl, float* __restrict__ out) {
  int t = threadIdx.x;  // 128 = 64 graphs x 2 classes
  int g = t >> 1, c = t & 1;
  int cnt = ends[g] - starts[g];
  if (cnt < 0) cnt = 0;
  float inv = 1.f / (float)(cnt > 0 ? cnt : 1);
  float acc = 0.f;
  for (int k = 0; k < FD; ++k) acc += psum[g * FD + k] * Wl[k * 2 + c];
  out[g * 2 + c] = acc * inv + bl[c];
}

// ---------------- host ----------------

extern "C" void kernel_launch(void* const* d_in, const int* in_sizes, int n_in,
                              void* d_out, int out_size, void* d_ws, size_t ws_size,
                              hipStream_t stream) {
  const float* x  = (const float*)d_in[0];
  const int* ei   = (const int*)d_in[1];
  const int* bat  = (const int*)d_in[2];
  const float* W1 = (const float*)d_in[3];
  const float* b1 = (const float*)d_in[4];
  const float* W2 = (const float*)d_in[5];
  const float* b2 = (const float*)d_in[6];
  const float* W3 = (const float*)d_in[7];
  const float* b3 = (const float*)d_in[8];
  const float* Wl = (const float*)d_in[9];
  const float* bl = (const float*)d_in[10];
  float* out = (float*)d_out;

  char* ws = (char*)d_ws;
  size_t off = 0;
  auto alloc = [&](size_t bytes) {
    void* p = ws + off;
    off += (bytes + 255) & ~(size_t)255;
    return p;
  };
  int* counts  = (int*)alloc(NN * 4);
  int* cursor  = (int*)alloc(NN * 4);
  int* indptr  = (int*)alloc((NN + 1) * 4);
  float* dinv  = (float*)alloc(NN * 4);
  int* bsum    = (int*)alloc(NB * 4);
  int* eb      = (int*)alloc(NB * 4);
  int* starts  = (int*)alloc(NG * 4);
  int* ends    = (int*)alloc(NG * 4);
  float* psum  = (float*)alloc(NG * FD * 4);
  int* srcs    = (int*)alloc(NE * 4);
  float* nrms  = (float*)alloc(NE * 4);
  unsigned short* xb   = (unsigned short*)alloc((size_t)NN * FD * 2);
  unsigned short* Hb   = (unsigned short*)alloc((size_t)NN * FD * 2);
  unsigned short* Abuf = (unsigned short*)alloc((size_t)NN * FD * 2);
  unsigned short* WT1h = (unsigned short*)alloc(FD * FD * 2);
  unsigned short* WT1l = (unsigned short*)alloc(FD * FD * 2);
  unsigned short* WT2h = (unsigned short*)alloc(FD * FD * 2);
  unsigned short* WT2l = (unsigned short*)alloc(FD * FD * 2);
  unsigned short* WT3h = (unsigned short*)alloc(FD * FD * 2);
  unsigned short* WT3l = (unsigned short*)alloc(FD * FD * 2);

  const int* row = ei;
  const int* col = ei + NE;

  hipMemsetAsync(counts, 0, NN * 4, stream);
  hipMemsetAsync(cursor, 0, NN * 4, stream);
  k_init<<<32, 256, 0, stream>>>(psum);
  k_castx<<<(NN * FD / 4 + 255) / 256, 256, 0, stream>>>(x, (uint2*)xb);
  k_castW<<<(FD * FD + 255) / 256, 256, 0, stream>>>(W1, WT1h, WT1l);
  k_castW<<<(FD * FD + 255) / 256, 256, 0, stream>>>(W2, WT2h, WT2l);
  k_castW<<<(FD * FD + 255) / 256, 256, 0, stream>>>(W3, WT3h, WT3l);
  k_ranges<<<(NN + 255) / 256, 256, 0, stream>>>(bat, starts, ends);
  k_count<<<(NE + 255) / 256, 256, 0, stream>>>(col, counts);
  k_dinv<<<(NN + 255) / 256, 256, 0, stream>>>(counts, dinv);
  k_bsum<<<NB, 1024, 0, stream>>>(counts, bsum);
  k_bscan<<<1, 128, 0, stream>>>(bsum, eb);
  k_scan2<<<NB, 1024, 0, stream>>>(counts, eb, indptr);
  k_fill<<<(NE + 255) / 256, 256, 0, stream>>>(row, col, indptr, cursor, dinv, srcs, nrms);

  int gemmGrid = (NN + 127) / 128;
  int aggGrid = (NN + 3) / 4;

  k_gemm<<<gemmGrid, 256, 0, stream>>>(xb, WT1h, WT1l, Hb, NN);
  k_agg<<<aggGrid, 256, 0, stream>>>((const unsigned*)Hb, indptr, srcs, nrms, dinv, b1,
                                     (unsigned*)Abuf, 1);
  k_gemm<<<gemmGrid, 256, 0, stream>>>(Abuf, WT2h, WT2l, Hb, NN);
  k_agg<<<aggGrid, 256, 0, stream>>>((const unsigned*)Hb, indptr, srcs, nrms, dinv, b2,
                                     (unsigned*)Abuf, 1);
  k_gemm<<<gemmGrid, 256, 0, stream>>>(Abuf, WT3h, WT3l, Hb, NN);
  k_agg<<<aggGrid, 256, 0, stream>>>((const unsigned*)Hb, indptr, srcs, nrms, dinv, b3,
                                     (unsigned*)Abuf, 0);

  k_pool<<<NG * 8, 128, 0, stream>>>(Abuf, starts, ends, psum);
  k_head<<<1, 128, 0, stream>>>(psum, starts, ends, Wl, bl, out);
}

// Round 4
// 341.601 us; speedup vs baseline: 3.9758x; 1.2794x over previous
//
#include <hip/hip_runtime.h>

#define NN 100000
#define NE 600000
#define NG 64
#define FD 128
#define NB 98   // scan blocks of 1024: 98*1024 >= NN

typedef __attribute__((ext_vector_type(8))) short s8v;
typedef __attribute__((ext_vector_type(4))) float f4v;

__device__ inline float bflo(unsigned u) { return __uint_as_float(u << 16); }
__device__ inline float bfhi(unsigned u) { return __uint_as_float(u & 0xFFFF0000u); }
__device__ inline unsigned f2bfbits(float f) {  // round-to-nearest-even
  unsigned x = __float_as_uint(f);
  return (x + 0x7FFFu + ((x >> 16) & 1u)) >> 16;
}
__device__ inline unsigned pack2(float a, float b) { return f2bfbits(a) | (f2bfbits(b) << 16); }

// ---------------- weight cast: W f32 [K][N] -> WThi/WTlo bf16 [N][K] ----------------
__global__ void k_castW(const float* __restrict__ W, unsigned short* __restrict__ WThi,
                        unsigned short* __restrict__ WTlo) {
  int e = blockIdx.x * 256 + threadIdx.x;
  if (e >= FD * FD) return;
  int k = e >> 7, n = e & 127;
  float v = W[e];
  unsigned hb = f2bfbits(v);
  float hf = __uint_as_float(hb << 16);
  unsigned lb = f2bfbits(v - hf);
  WThi[n * FD + k] = (unsigned short)hb;
  WTlo[n * FD + k] = (unsigned short)lb;
}

// ---------------- degree / CSR build ----------------

__global__ void k_init(float* psum) {
  int i = blockIdx.x * 256 + threadIdx.x;
  if (i < NG * FD) psum[i] = 0.f;
}

__global__ void k_count(const int* __restrict__ col, int* __restrict__ counts) {
  int e = blockIdx.x * 256 + threadIdx.x;
  if (e < NE) atomicAdd(&counts[col[e]], 1);
}

__global__ void k_dinv(const int* __restrict__ counts, float* __restrict__ dinv) {
  int n = blockIdx.x * 256 + threadIdx.x;
  if (n < NN) dinv[n] = rsqrtf((float)counts[n] + 1.0f);
}

// 3-phase scan
__global__ void k_bsum(const int* __restrict__ counts, int* __restrict__ bsum) {
  __shared__ int wsm[16];
  int b = blockIdx.x, t = threadIdx.x;
  int i = b * 1024 + t;
  int x = (i < NN) ? counts[i] : 0;
#pragma unroll
  for (int d = 32; d; d >>= 1) x += __shfl_down(x, d);
  if ((t & 63) == 0) wsm[t >> 6] = x;
  __syncthreads();
  if (t < 16) {
    int s = wsm[t];
#pragma unroll
    for (int d = 8; d; d >>= 1) s += __shfl_down(s, d);
    if (t == 0) bsum[b] = s;
  }
}

__global__ void k_bscan(const int* __restrict__ bsum, int* __restrict__ eb) {
  __shared__ int w0;
  int t = threadIdx.x;  // 128
  int x = (t < NB) ? bsum[t] : 0;
  int lane = t & 63;
  int inc = x;
#pragma unroll
  for (int d = 1; d < 64; d <<= 1) { int y = __shfl_up(inc, d); if (lane >= d) inc += y; }
  if (t == 63) w0 = inc;
  __syncthreads();
  int off = (t >= 64) ? w0 : 0;
  if (t < NB) eb[t] = off + inc - x;  // exclusive
}

__global__ void k_scan2(const int* __restrict__ counts, const int* __restrict__ eb,
                        int* __restrict__ indptr) {
  __shared__ int wsm[16];
  int b = blockIdx.x, t = threadIdx.x;
  int i = b * 1024 + t;
  int x = (i < NN) ? counts[i] : 0;
  int lane = t & 63, wid = t >> 6;
  int inc = x;
#pragma unroll
  for (int d = 1; d < 64; d <<= 1) { int y = __shfl_up(inc, d); if (lane >= d) inc += y; }
  if (lane == 63) wsm[wid] = inc;
  __syncthreads();
  if (wid == 0) {
    int s = (lane < 16) ? wsm[lane] : 0;
#pragma unroll
    for (int d = 1; d < 16; d <<= 1) { int y = __shfl_up(s, d); if (lane >= d) s += y; }
    if (lane < 16) wsm[lane] = s;
  }
  __syncthreads();
  int woff = wid ? wsm[wid - 1] : 0;
  if (i < NN) indptr[i + 1] = eb[b] + woff + inc;
  if (i == 0) indptr[0] = 0;
}

// combined edge record: {src, nrm}
__global__ void k_fill(const int* __restrict__ row, const int* __restrict__ col,
                       const int* __restrict__ indptr, int* __restrict__ cursor,
                       const float* __restrict__ dinv, uint2* __restrict__ edges) {
  int e = blockIdx.x * 256 + threadIdx.x;
  if (e >= NE) return;
  int c = col[e], r = row[e];
  int p = indptr[c] + atomicAdd(&cursor[c], 1);
  edges[p] = make_uint2((unsigned)r, __float_as_uint(dinv[r] * dinv[c]));
}

// batch is sorted: ranges by boundary detection
__global__ void k_ranges(const int* __restrict__ batch, int* __restrict__ starts,
                         int* __restrict__ ends) {
  int n = blockIdx.x * 256 + threadIdx.x;
  if (n >= NN) return;
  int g = batch[n];
  if (n == 0) {
    starts[g] = 0;
    for (int q = 0; q < g; ++q) { starts[q] = 0; ends[q] = 0; }
  } else {
    int gp = batch[n - 1];
    if (gp != g) {
      ends[gp] = n;
      starts[g] = n;
      for (int q = gp + 1; q < g; ++q) { starts[q] = n; ends[q] = n; }
    }
  }
  if (n == NN - 1) {
    ends[g] = NN;
    for (int q = g + 1; q < NG; ++q) { starts[q] = NN; ends[q] = NN; }
  }
}

// ---------------- MFMA GEMM: Hb[M,128] = A[M,128] @ (WThi+WTlo)^T ----------------
// 256 threads = 4 waves; 128 rows/block. A is bf16 (F32A=0) or f32 (F32A=1).
template <int F32A>
__global__ __launch_bounds__(256) void k_gemm(const void* __restrict__ Aab,
                                              const unsigned short* __restrict__ WThi,
                                              const unsigned short* __restrict__ WTlo,
                                              unsigned short* __restrict__ Hb, int M) {
  __shared__ unsigned short wt[128][136];
  int t = threadIdx.x, lane = t & 63, w = t >> 6;
  int rowBase = blockIdx.x * 128 + w * 32;
  int r16 = lane & 15, kg = lane >> 4;

  f4v acc[2][8];
#pragma unroll
  for (int rt = 0; rt < 2; ++rt)
#pragma unroll
    for (int n = 0; n < 8; ++n) acc[rt][n] = (f4v){0.f, 0.f, 0.f, 0.f};

  // A fragments: lane holds A[row=r16][k = c*32 + kg*8 + j]
  s8v afr[2][4];
#pragma unroll
  for (int rt = 0; rt < 2; ++rt) {
    int ar = rowBase + rt * 16 + r16;
    if (ar > M - 1) ar = M - 1;
    if (F32A) {
      const float* ap = (const float*)Aab + (size_t)ar * FD + kg * 8;
#pragma unroll
      for (int c = 0; c < 4; ++c) {
        float4 p0 = *(const float4*)(ap + c * 32);
        float4 p1 = *(const float4*)(ap + c * 32 + 4);
        s8v f;
        f[0] = (short)f2bfbits(p0.x); f[1] = (short)f2bfbits(p0.y);
        f[2] = (short)f2bfbits(p0.z); f[3] = (short)f2bfbits(p0.w);
        f[4] = (short)f2bfbits(p1.x); f[5] = (short)f2bfbits(p1.y);
        f[6] = (short)f2bfbits(p1.z); f[7] = (short)f2bfbits(p1.w);
        afr[rt][c] = f;
      }
    } else {
      const unsigned short* ap = (const unsigned short*)Aab + (size_t)ar * FD + kg * 8;
#pragma unroll
      for (int c = 0; c < 4; ++c) afr[rt][c] = *(const s8v*)(ap + c * 32);
    }
  }

  for (int pass = 0; pass < 2; ++pass) {
    const unsigned short* Wg = pass ? WTlo : WThi;
    {  // stage 128x128 bf16 into LDS
      int n = t >> 1, koff = (t & 1) * 64;
      const unsigned short* src = Wg + n * FD + koff;
#pragma unroll
      for (int j = 0; j < 8; ++j)
        *(s8v*)&wt[n][koff + j * 8] = *(const s8v*)(src + j * 8);
    }
    __syncthreads();
#pragma unroll
    for (int n = 0; n < 8; ++n) {
#pragma unroll
      for (int c = 0; c < 4; ++c) {
        s8v bfr = *(const s8v*)&wt[n * 16 + r16][c * 32 + kg * 8];
        acc[0][n] = __builtin_amdgcn_mfma_f32_16x16x32_bf16(afr[0][c], bfr, acc[0][n], 0, 0, 0);
        acc[1][n] = __builtin_amdgcn_mfma_f32_16x16x32_bf16(afr[1][c], bfr, acc[1][n], 0, 0, 0);
      }
    }
    __syncthreads();
  }

  // epilogue: D lane layout col = r16, row = kg*4 + j
#pragma unroll
  for (int rt = 0; rt < 2; ++rt)
#pragma unroll
    for (int j = 0; j < 4; ++j) {
      int r = rowBase + rt * 16 + kg * 4 + j;
      if (r < M) {
#pragma unroll
        for (int n = 0; n < 8; ++n)
          Hb[(size_t)r * FD + n * 16 + r16] = (unsigned short)f2bfbits(acc[rt][n][j]);
      }
    }
}

// ---------------- aggregation: bf16 in/out, f32 accumulate, 4-way edge unroll ----------------
__global__ __launch_bounds__(256) void k_agg(const unsigned* __restrict__ H2,
                                             const int* __restrict__ indptr,
                                             const uint2* __restrict__ edges,
                                             const float* __restrict__ dinv,
                                             const float* __restrict__ bias,
                                             unsigned* __restrict__ out2, int relu) {
  int n = blockIdx.x * 4 + (threadIdx.x >> 6);
  int lane = threadIdx.x & 63;
  if (n >= NN) return;
  float dv = dinv[n];
  float s2 = dv * dv;
  unsigned u = H2[(size_t)n * 64 + lane];
  float a0 = s2 * bflo(u), a1 = s2 * bfhi(u);
  int e0 = indptr[n], e1 = indptr[n + 1];
  int e = e0;
  for (; e + 3 < e1; e += 4) {
    uint2 q0 = edges[e], q1 = edges[e + 1], q2 = edges[e + 2], q3 = edges[e + 3];
    unsigned v0 = H2[(size_t)q0.x * 64 + lane];
    unsigned v1 = H2[(size_t)q1.x * 64 + lane];
    unsigned v2 = H2[(size_t)q2.x * 64 + lane];
    unsigned v3 = H2[(size_t)q3.x * 64 + lane];
    float w0 = __uint_as_float(q0.y), w1 = __uint_as_float(q1.y);
    float w2 = __uint_as_float(q2.y), w3 = __uint_as_float(q3.y);
    a0 += w0 * bflo(v0); a1 += w0 * bfhi(v0);
    a0 += w1 * bflo(v1); a1 += w1 * bfhi(v1);
    a0 += w2 * bflo(v2); a1 += w2 * bfhi(v2);
    a0 += w3 * bflo(v3); a1 += w3 * bfhi(v3);
  }
  if (e + 1 < e1) {
    uint2 q0 = edges[e], q1 = edges[e + 1];
    unsigned v0 = H2[(size_t)q0.x * 64 + lane];
    unsigned v1 = H2[(size_t)q1.x * 64 + lane];
    float w0 = __uint_as_float(q0.y), w1 = __uint_as_float(q1.y);
    a0 += w0 * bflo(v0); a1 += w0 * bfhi(v0);
    a0 += w1 * bflo(v1); a1 += w1 * bfhi(v1);
    e += 2;
  }
  if (e < e1) {
    uint2 q = edges[e];
    unsigned v = H2[(size_t)q.x * 64 + lane];
    float wgt = __uint_as_float(q.y);
    a0 += wgt * bflo(v); a1 += wgt * bfhi(v);
  }
  a0 += bias[lane * 2];
  a1 += bias[lane * 2 + 1];
  if (relu) { a0 = fmaxf(a0, 0.f); a1 = fmaxf(a1, 0.f); }
  out2[(size_t)n * 64 + lane] = pack2(a0, a1);
}

// ---------------- mean pool (bf16 input) ----------------
__global__ void k_pool(const unsigned short* __restrict__ Ab, const int* __restrict__ starts,
                       const int* __restrict__ ends, float* __restrict__ psum) {
  int g = blockIdx.x >> 3;
  int s = blockIdx.x & 7;
  int f = threadIdx.x;  // 128
  int n0 = starts[g], n1 = ends[g];
  if (n1 <= n0) return;
  long long len = n1 - n0;
  int a = n0 + (int)(len * s / 8);
  int b = n0 + (int)(len * (s + 1) / 8);
  float acc = 0.f;
  for (int n = a; n < b; ++n) acc += __uint_as_float(((unsigned)Ab[(size_t)n * FD + f]) << 16);
  atomicAdd(&psum[g * FD + f], acc);
}

__global__ void k_head(const float* __restrict__ psum, const int* __restrict__ starts,
                       const int* __restrict__ ends, const float* __restrict__ Wl,
                       const float* __restrict__ bl, float* __restrict__ out) {
  int t = threadIdx.x;  // 128 = 64 graphs x 2 classes
  int g = t >> 1, c = t & 1;
  int cnt = ends[g] - starts[g];
  if (cnt < 0) cnt = 0;
  float inv = 1.f / (float)(cnt > 0 ? cnt : 1);
  float acc = 0.f;
  for (int k = 0; k < FD; ++k) acc += psum[g * FD + k] * Wl[k * 2 + c];
  out[g * 2 + c] = acc * inv + bl[c];
}

// ---------------- host ----------------

extern "C" void kernel_launch(void* const* d_in, const int* in_sizes, int n_in,
                              void* d_out, int out_size, void* d_ws, size_t ws_size,
                              hipStream_t stream) {
  const float* x  = (const float*)d_in[0];
  const int* ei   = (const int*)d_in[1];
  const int* bat  = (const int*)d_in[2];
  const float* W1 = (const float*)d_in[3];
  const float* b1 = (const float*)d_in[4];
  const float* W2 = (const float*)d_in[5];
  const float* b2 = (const float*)d_in[6];
  const float* W3 = (const float*)d_in[7];
  const float* b3 = (const float*)d_in[8];
  const float* Wl = (const float*)d_in[9];
  const float* bl = (const float*)d_in[10];
  float* out = (float*)d_out;

  char* ws = (char*)d_ws;
  size_t off = 0;
  auto alloc = [&](size_t bytes) {
    void* p = ws + off;
    off += (bytes + 255) & ~(size_t)255;
    return p;
  };
  int* counts  = (int*)alloc(NN * 4);
  int* cursor  = (int*)alloc(NN * 4);
  int* indptr  = (int*)alloc((NN + 1) * 4);
  float* dinv  = (float*)alloc(NN * 4);
  int* bsum    = (int*)alloc(NB * 4);
  int* eb      = (int*)alloc(NB * 4);
  int* starts  = (int*)alloc(NG * 4);
  int* ends    = (int*)alloc(NG * 4);
  float* psum  = (float*)alloc(NG * FD * 4);
  uint2* edges = (uint2*)alloc((size_t)NE * 8);
  unsigned short* Hb   = (unsigned short*)alloc((size_t)NN * FD * 2);
  unsigned short* Abuf = (unsigned short*)alloc((size_t)NN * FD * 2);
  unsigned short* WT1h = (unsigned short*)alloc(FD * FD * 2);
  unsigned short* WT1l = (unsigned short*)alloc(FD * FD * 2);
  unsigned short* WT2h = (unsigned short*)alloc(FD * FD * 2);
  unsigned short* WT2l = (unsigned short*)alloc(FD * FD * 2);
  unsigned short* WT3h = (unsigned short*)alloc(FD * FD * 2);
  unsigned short* WT3l = (unsigned short*)alloc(FD * FD * 2);

  const int* row = ei;
  const int* col = ei + NE;

  hipMemsetAsync(counts, 0, NN * 4, stream);
  hipMemsetAsync(cursor, 0, NN * 4, stream);
  k_init<<<32, 256, 0, stream>>>(psum);
  k_castW<<<(FD * FD + 255) / 256, 256, 0, stream>>>(W1, WT1h, WT1l);
  k_castW<<<(FD * FD + 255) / 256, 256, 0, stream>>>(W2, WT2h, WT2l);
  k_castW<<<(FD * FD + 255) / 256, 256, 0, stream>>>(W3, WT3h, WT3l);
  k_ranges<<<(NN + 255) / 256, 256, 0, stream>>>(bat, starts, ends);
  k_count<<<(NE + 255) / 256, 256, 0, stream>>>(col, counts);
  k_dinv<<<(NN + 255) / 256, 256, 0, stream>>>(counts, dinv);
  k_bsum<<<NB, 1024, 0, stream>>>(counts, bsum);
  k_bscan<<<1, 128, 0, stream>>>(bsum, eb);
  k_scan2<<<NB, 1024, 0, stream>>>(counts, eb, indptr);
  k_fill<<<(NE + 255) / 256, 256, 0, stream>>>(row, col, indptr, cursor, dinv, edges);

  int gemmGrid = (NN + 127) / 128;
  int aggGrid = (NN + 3) / 4;

  k_gemm<1><<<gemmGrid, 256, 0, stream>>>(x, WT1h, WT1l, Hb, NN);
  k_agg<<<aggGrid, 256, 0, stream>>>((const unsigned*)Hb, indptr, edges, dinv, b1,
                                     (unsigned*)Abuf, 1);
  k_gemm<0><<<gemmGrid, 256, 0, stream>>>(Abuf, WT2h, WT2l, Hb, NN);
  k_agg<<<aggGrid, 256, 0, stream>>>((const unsigned*)Hb, indptr, edges, dinv, b2,
                                     (unsigned*)Abuf, 1);
  k_gemm<0><<<gemmGrid, 256, 0, stream>>>(Abuf, WT3h, WT3l, Hb, NN);
  k_agg<<<aggGrid, 256, 0, stream>>>((const unsigned*)Hb, indptr, edges, dinv, b3,
                                     (unsigned*)Abuf, 0);

  k_pool<<<NG * 8, 128, 0, stream>>>(Abuf, starts, ends, psum);
  k_head<<<1, 128, 0, stream>>>(psum, starts, ends, Wl, bl, out);
}

// Round 5
// 303.826 us; speedup vs baseline: 4.4701x; 1.1243x over previous
//
#include <hip/hip_runtime.h>

#define NN 100000
#define NE 600000
#define NG 64
#define FD 128
#define NB 98   // scan blocks of 1024: 98*1024 >= NN

typedef __attribute__((ext_vector_type(8))) short s8v;
typedef __attribute__((ext_vector_type(4))) float f4v;

__device__ inline float bflo(unsigned u) { return __uint_as_float(u << 16); }
__device__ inline float bfhi(unsigned u) { return __uint_as_float(u & 0xFFFF0000u); }
__device__ inline unsigned f2bfbits(float f) {  // round-to-nearest-even
  unsigned x = __float_as_uint(f);
  return (x + 0x7FFFu + ((x >> 16) & 1u)) >> 16;
}
__device__ inline unsigned pack2(float a, float b) { return f2bfbits(a) | (f2bfbits(b) << 16); }

// ---------------- weight cast: W f32 [K][N] -> WThi/WTlo bf16 [N][K], 3 weights in one ----------------
__global__ void k_castW3(const float* __restrict__ W1, const float* __restrict__ W2,
                         const float* __restrict__ W3, unsigned short* __restrict__ WTh,
                         unsigned short* __restrict__ WTl) {
  int e = blockIdx.x * 256 + threadIdx.x;   // grid covers 3*FD*FD
  int which = e / (FD * FD);
  int r = e - which * (FD * FD);
  if (which >= 3) return;
  const float* W = which == 0 ? W1 : (which == 1 ? W2 : W3);
  int k = r >> 7, n = r & 127;
  float v = W[r];
  unsigned hb = f2bfbits(v);
  float hf = __uint_as_float(hb << 16);
  unsigned lb = f2bfbits(v - hf);
  WTh[which * FD * FD + n * FD + k] = (unsigned short)hb;
  WTl[which * FD * FD + n * FD + k] = (unsigned short)lb;
}

// ---------------- degree / CSR build ----------------

__global__ void k_init(float* psum) {
  int i = blockIdx.x * 256 + threadIdx.x;
  if (i < NG * FD) psum[i] = 0.f;
}

__global__ void k_count(const int* __restrict__ col, int* __restrict__ counts) {
  int e = blockIdx.x * 256 + threadIdx.x;
  if (e < NE) atomicAdd(&counts[col[e]], 1);
}

__global__ void k_dinv(const int* __restrict__ counts, float* __restrict__ dinv) {
  int n = blockIdx.x * 256 + threadIdx.x;
  if (n < NN) dinv[n] = rsqrtf((float)counts[n] + 1.0f);
}

// 3-phase scan
__global__ void k_bsum(const int* __restrict__ counts, int* __restrict__ bsum) {
  __shared__ int wsm[16];
  int b = blockIdx.x, t = threadIdx.x;
  int i = b * 1024 + t;
  int x = (i < NN) ? counts[i] : 0;
#pragma unroll
  for (int d = 32; d; d >>= 1) x += __shfl_down(x, d);
  if ((t & 63) == 0) wsm[t >> 6] = x;
  __syncthreads();
  if (t < 16) {
    int s = wsm[t];
#pragma unroll
    for (int d = 8; d; d >>= 1) s += __shfl_down(s, d);
    if (t == 0) bsum[b] = s;
  }
}

__global__ void k_bscan(const int* __restrict__ bsum, int* __restrict__ eb) {
  __shared__ int w0;
  int t = threadIdx.x;  // 128
  int x = (t < NB) ? bsum[t] : 0;
  int lane = t & 63;
  int inc = x;
#pragma unroll
  for (int d = 1; d < 64; d <<= 1) { int y = __shfl_up(inc, d); if (lane >= d) inc += y; }
  if (t == 63) w0 = inc;
  __syncthreads();
  int off = (t >= 64) ? w0 : 0;
  if (t < NB) eb[t] = off + inc - x;  // exclusive
}

__global__ void k_scan2(const int* __restrict__ counts, const int* __restrict__ eb,
                        int* __restrict__ indptr) {
  __shared__ int wsm[16];
  int b = blockIdx.x, t = threadIdx.x;
  int i = b * 1024 + t;
  int x = (i < NN) ? counts[i] : 0;
  int lane = t & 63, wid = t >> 6;
  int inc = x;
#pragma unroll
  for (int d = 1; d < 64; d <<= 1) { int y = __shfl_up(inc, d); if (lane >= d) inc += y; }
  if (lane == 63) wsm[wid] = inc;
  __syncthreads();
  if (wid == 0) {
    int s = (lane < 16) ? wsm[lane] : 0;
#pragma unroll
    for (int d = 1; d < 16; d <<= 1) { int y = __shfl_up(s, d); if (lane >= d) s += y; }
    if (lane < 16) wsm[lane] = s;
  }
  __syncthreads();
  int woff = wid ? wsm[wid - 1] : 0;
  if (i < NN) indptr[i + 1] = eb[b] + woff + inc;
  if (i == 0) indptr[0] = 0;
}

// combined edge record: {src, nrm}
__global__ void k_fill(const int* __restrict__ row, const int* __restrict__ col,
                       const int* __restrict__ indptr, int* __restrict__ cursor,
                       const float* __restrict__ dinv, uint2* __restrict__ edges) {
  int e = blockIdx.x * 256 + threadIdx.x;
  if (e >= NE) return;
  int c = col[e], r = row[e];
  int p = indptr[c] + atomicAdd(&cursor[c], 1);
  edges[p] = make_uint2((unsigned)r, __float_as_uint(dinv[r] * dinv[c]));
}

// batch is sorted: ranges by boundary detection
__global__ void k_ranges(const int* __restrict__ batch, int* __restrict__ starts,
                         int* __restrict__ ends) {
  int n = blockIdx.x * 256 + threadIdx.x;
  if (n >= NN) return;
  int g = batch[n];
  if (n == 0) {
    starts[g] = 0;
    for (int q = 0; q < g; ++q) { starts[q] = 0; ends[q] = 0; }
  } else {
    int gp = batch[n - 1];
    if (gp != g) {
      ends[gp] = n;
      starts[g] = n;
      for (int q = gp + 1; q < g; ++q) { starts[q] = n; ends[q] = n; }
    }
  }
  if (n == NN - 1) {
    ends[g] = NN;
    for (int q = g + 1; q < NG; ++q) { starts[q] = NN; ends[q] = NN; }
  }
}

// ---------------- MFMA GEMM: Hb[M,128] = A[M,128] @ (WThi+WTlo)^T ----------------
template <int F32A>
__global__ __launch_bounds__(256) void k_gemm(const void* __restrict__ Aab,
                                              const unsigned short* __restrict__ WThi,
                                              const unsigned short* __restrict__ WTlo,
                                              unsigned short* __restrict__ Hb, int M) {
  __shared__ unsigned short wt[128][136];
  int t = threadIdx.x, lane = t & 63, w = t >> 6;
  int rowBase = blockIdx.x * 128 + w * 32;
  int r16 = lane & 15, kg = lane >> 4;

  f4v acc[2][8];
#pragma unroll
  for (int rt = 0; rt < 2; ++rt)
#pragma unroll
    for (int n = 0; n < 8; ++n) acc[rt][n] = (f4v){0.f, 0.f, 0.f, 0.f};

  s8v afr[2][4];
#pragma unroll
  for (int rt = 0; rt < 2; ++rt) {
    int ar = rowBase + rt * 16 + r16;
    if (ar > M - 1) ar = M - 1;
    if (F32A) {
      const float* ap = (const float*)Aab + (size_t)ar * FD + kg * 8;
#pragma unroll
      for (int c = 0; c < 4; ++c) {
        float4 p0 = *(const float4*)(ap + c * 32);
        float4 p1 = *(const float4*)(ap + c * 32 + 4);
        s8v f;
        f[0] = (short)f2bfbits(p0.x); f[1] = (short)f2bfbits(p0.y);
        f[2] = (short)f2bfbits(p0.z); f[3] = (short)f2bfbits(p0.w);
        f[4] = (short)f2bfbits(p1.x); f[5] = (short)f2bfbits(p1.y);
        f[6] = (short)f2bfbits(p1.z); f[7] = (short)f2bfbits(p1.w);
        afr[rt][c] = f;
      }
    } else {
      const unsigned short* ap = (const unsigned short*)Aab + (size_t)ar * FD + kg * 8;
#pragma unroll
      for (int c = 0; c < 4; ++c) afr[rt][c] = *(const s8v*)(ap + c * 32);
    }
  }

  for (int pass = 0; pass < 2; ++pass) {
    const unsigned short* Wg = pass ? WTlo : WThi;
    {
      int n = t >> 1, koff = (t & 1) * 64;
      const unsigned short* src = Wg + n * FD + koff;
#pragma unroll
      for (int j = 0; j < 8; ++j)
        *(s8v*)&wt[n][koff + j * 8] = *(const s8v*)(src + j * 8);
    }
    __syncthreads();
#pragma unroll
    for (int n = 0; n < 8; ++n) {
#pragma unroll
      for (int c = 0; c < 4; ++c) {
        s8v bfr = *(const s8v*)&wt[n * 16 + r16][c * 32 + kg * 8];
        acc[0][n] = __builtin_amdgcn_mfma_f32_16x16x32_bf16(afr[0][c], bfr, acc[0][n], 0, 0, 0);
        acc[1][n] = __builtin_amdgcn_mfma_f32_16x16x32_bf16(afr[1][c], bfr, acc[1][n], 0, 0, 0);
      }
    }
    __syncthreads();
  }

#pragma unroll
  for (int rt = 0; rt < 2; ++rt)
#pragma unroll
    for (int j = 0; j < 4; ++j) {
      int r = rowBase + rt * 16 + kg * 4 + j;
      if (r < M) {
#pragma unroll
        for (int n = 0; n < 8; ++n)
          Hb[(size_t)r * FD + n * 16 + r16] = (unsigned short)f2bfbits(acc[rt][n][j]);
      }
    }
}

// ---------------- aggregation: bf16 in/out, f32 accumulate, 4-way edge unroll ----------------
__global__ __launch_bounds__(256) void k_agg(const unsigned* __restrict__ H2,
                                             const int* __restrict__ indptr,
                                             const uint2* __restrict__ edges,
                                             const float* __restrict__ dinv,
                                             const float* __restrict__ bias,
                                             unsigned* __restrict__ out2, int relu) {
  int n = blockIdx.x * 4 + (threadIdx.x >> 6);
  int lane = threadIdx.x & 63;
  if (n >= NN) return;
  float dv = dinv[n];
  float s2 = dv * dv;
  unsigned u = H2[(size_t)n * 64 + lane];
  float a0 = s2 * bflo(u), a1 = s2 * bfhi(u);
  int e0 = indptr[n], e1 = indptr[n + 1];
  int e = e0;
  for (; e + 3 < e1; e += 4) {
    uint2 q0 = edges[e], q1 = edges[e + 1], q2 = edges[e + 2], q3 = edges[e + 3];
    unsigned v0 = H2[(size_t)q0.x * 64 + lane];
    unsigned v1 = H2[(size_t)q1.x * 64 + lane];
    unsigned v2 = H2[(size_t)q2.x * 64 + lane];
    unsigned v3 = H2[(size_t)q3.x * 64 + lane];
    float w0 = __uint_as_float(q0.y), w1 = __uint_as_float(q1.y);
    float w2 = __uint_as_float(q2.y), w3 = __uint_as_float(q3.y);
    a0 += w0 * bflo(v0); a1 += w0 * bfhi(v0);
    a0 += w1 * bflo(v1); a1 += w1 * bfhi(v1);
    a0 += w2 * bflo(v2); a1 += w2 * bfhi(v2);
    a0 += w3 * bflo(v3); a1 += w3 * bfhi(v3);
  }
  if (e + 1 < e1) {
    uint2 q0 = edges[e], q1 = edges[e + 1];
    unsigned v0 = H2[(size_t)q0.x * 64 + lane];
    unsigned v1 = H2[(size_t)q1.x * 64 + lane];
    float w0 = __uint_as_float(q0.y), w1 = __uint_as_float(q1.y);
    a0 += w0 * bflo(v0); a1 += w0 * bfhi(v0);
    a0 += w1 * bflo(v1); a1 += w1 * bfhi(v1);
    e += 2;
  }
  if (e < e1) {
    uint2 q = edges[e];
    unsigned v = H2[(size_t)q.x * 64 + lane];
    float wgt = __uint_as_float(q.y);
    a0 += wgt * bflo(v); a1 += wgt * bfhi(v);
  }
  a0 += bias[lane * 2];
  a1 += bias[lane * 2 + 1];
  if (relu) { a0 = fmaxf(a0, 0.f); a1 = fmaxf(a1, 0.f); }
  out2[(size_t)n * 64 + lane] = pack2(a0, a1);
}

// ---------------- mean pool: wave per 64-node chunk, lanes cover row as bf16x2 ----------------
#define PW 64  // nodes per wave
__global__ __launch_bounds__(256) void k_pool(const unsigned* __restrict__ H2,
                                              const int* __restrict__ batch,
                                              float* __restrict__ psum) {
  int wgl = (blockIdx.x * 256 + threadIdx.x) >> 6;  // global wave id
  int lane = threadIdx.x & 63;
  int n0 = wgl * PW;
  if (n0 >= NN) return;
  int n1 = n0 + PW; if (n1 > NN) n1 = NN;
  int g0 = batch[n0], g1 = batch[n1 - 1];
  float a0 = 0.f, a1 = 0.f;
  if (g0 == g1) {
    // fast path: whole chunk in one graph, branch-free, 4-way unroll
    int n = n0;
    for (; n + 3 < n1; n += 4) {
      unsigned v0 = H2[(size_t)(n + 0) * 64 + lane];
      unsigned v1 = H2[(size_t)(n + 1) * 64 + lane];
      unsigned v2 = H2[(size_t)(n + 2) * 64 + lane];
      unsigned v3 = H2[(size_t)(n + 3) * 64 + lane];
      a0 += bflo(v0) + bflo(v1) + bflo(v2) + bflo(v3);
      a1 += bfhi(v0) + bfhi(v1) + bfhi(v2) + bfhi(v3);
    }
    for (; n < n1; ++n) {
      unsigned v = H2[(size_t)n * 64 + lane];
      a0 += bflo(v); a1 += bfhi(v);
    }
    atomicAdd(&psum[g0 * FD + lane * 2], a0);
    atomicAdd(&psum[g0 * FD + lane * 2 + 1], a1);
  } else {
    int g = g0;
    for (int n = n0; n < n1; ++n) {
      int gn = batch[n];
      if (gn != g) {
        atomicAdd(&psum[g * FD + lane * 2], a0);
        atomicAdd(&psum[g * FD + lane * 2 + 1], a1);
        a0 = 0.f; a1 = 0.f; g = gn;
      }
      unsigned v = H2[(size_t)n * 64 + lane];
      a0 += bflo(v); a1 += bfhi(v);
    }
    atomicAdd(&psum[g * FD + lane * 2], a0);
    atomicAdd(&psum[g * FD + lane * 2 + 1], a1);
  }
}

__global__ void k_head(const float* __restrict__ psum, const int* __restrict__ starts,
                       const int* __restrict__ ends, const float* __restrict__ Wl,
                       const float* __restrict__ bl, float* __restrict__ out) {
  int t = threadIdx.x;  // 128 = 64 graphs x 2 classes
  int g = t >> 1, c = t & 1;
  int cnt = ends[g] - starts[g];
  if (cnt < 0) cnt = 0;
  float inv = 1.f / (float)(cnt > 0 ? cnt : 1);
  float acc = 0.f;
  for (int k = 0; k < FD; ++k) acc += psum[g * FD + k] * Wl[k * 2 + c];
  out[g * 2 + c] = acc * inv + bl[c];
}

// ---------------- host ----------------

extern "C" void kernel_launch(void* const* d_in, const int* in_sizes, int n_in,
                              void* d_out, int out_size, void* d_ws, size_t ws_size,
                              hipStream_t stream) {
  const float* x  = (const float*)d_in[0];
  const int* ei   = (const int*)d_in[1];
  const int* bat  = (const int*)d_in[2];
  const float* W1 = (const float*)d_in[3];
  const float* b1 = (const float*)d_in[4];
  const float* W2 = (const float*)d_in[5];
  const float* b2 = (const float*)d_in[6];
  const float* W3 = (const float*)d_in[7];
  const float* b3 = (const float*)d_in[8];
  const float* Wl = (const float*)d_in[9];
  const float* bl = (const float*)d_in[10];
  float* out = (float*)d_out;

  char* ws = (char*)d_ws;
  size_t off = 0;
  auto alloc = [&](size_t bytes) {
    void* p = ws + off;
    off += (bytes + 255) & ~(size_t)255;
    return p;
  };
  int* counts  = (int*)alloc(NN * 4);
  int* cursor  = (int*)alloc(NN * 4);
  int* indptr  = (int*)alloc((NN + 1) * 4);
  float* dinv  = (float*)alloc(NN * 4);
  int* bsum    = (int*)alloc(NB * 4);
  int* eb      = (int*)alloc(NB * 4);
  int* starts  = (int*)alloc(NG * 4);
  int* ends    = (int*)alloc(NG * 4);
  float* psum  = (float*)alloc(NG * FD * 4);
  uint2* edges = (uint2*)alloc((size_t)NE * 8);
  unsigned short* Hb   = (unsigned short*)alloc((size_t)NN * FD * 2);
  unsigned short* Abuf = (unsigned short*)alloc((size_t)NN * FD * 2);
  unsigned short* WTh  = (unsigned short*)alloc(3 * FD * FD * 2);
  unsigned short* WTl  = (unsigned short*)alloc(3 * FD * FD * 2);

  const int* row = ei;
  const int* col = ei + NE;

  hipMemsetAsync(counts, 0, NN * 4, stream);
  hipMemsetAsync(cursor, 0, NN * 4, stream);
  k_init<<<32, 256, 0, stream>>>(psum);
  k_castW3<<<(3 * FD * FD + 255) / 256, 256, 0, stream>>>(W1, W2, W3, WTh, WTl);
  k_ranges<<<(NN + 255) / 256, 256, 0, stream>>>(bat, starts, ends);
  k_count<<<(NE + 255) / 256, 256, 0, stream>>>(col, counts);
  k_dinv<<<(NN + 255) / 256, 256, 0, stream>>>(counts, dinv);
  k_bsum<<<NB, 1024, 0, stream>>>(counts, bsum);
  k_bscan<<<1, 128, 0, stream>>>(bsum, eb);
  k_scan2<<<NB, 1024, 0, stream>>>(counts, eb, indptr);
  k_fill<<<(NE + 255) / 256, 256, 0, stream>>>(row, col, indptr, cursor, dinv, edges);

  int gemmGrid = (NN + 127) / 128;
  int aggGrid = (NN + 3) / 4;
  int poolGrid = ((NN + PW - 1) / PW * 64 + 255) / 256;

  k_gemm<1><<<gemmGrid, 256, 0, stream>>>(x, WTh, WTl, Hb, NN);
  k_agg<<<aggGrid, 256, 0, stream>>>((const unsigned*)Hb, indptr, edges, dinv, b1,
                                     (unsigned*)Abuf, 1);
  k_gemm<0><<<gemmGrid, 256, 0, stream>>>(Abuf, WTh + FD * FD, WTl + FD * FD, Hb, NN);
  k_agg<<<aggGrid, 256, 0, stream>>>((const unsigned*)Hb, indptr, edges, dinv, b2,
                                     (unsigned*)Abuf, 1);
  k_gemm<0><<<gemmGrid, 256, 0, stream>>>(Abuf, WTh + 2 * FD * FD, WTl + 2 * FD * FD, Hb, NN);
  k_agg<<<aggGrid, 256, 0, stream>>>((const unsigned*)Hb, indptr, edges, dinv, b3,
                                     (unsigned*)Abuf, 0);

  k_pool<<<poolGrid, 256, 0, stream>>>((const unsigned*)Abuf, bat, psum);
  k_head<<<1, 128, 0, stream>>>(psum, starts, ends, Wl, bl, out);
}

// Round 6
// 278.182 us; speedup vs baseline: 4.8821x; 1.0922x over previous
//
#include <hip/hip_runtime.h>

#define NN 100000
#define NE 600000
#define NG 64
#define FD 128
#define NB 98   // scan blocks of 1024: 98*1024 >= NN
#define EPAD 900000  // padded edge capacity: NE + 3*NN

typedef __attribute__((ext_vector_type(8))) short s8v;
typedef __attribute__((ext_vector_type(4))) float f4v;

__device__ inline float bflo(unsigned u) { return __uint_as_float(u << 16); }
__device__ inline float bfhi(unsigned u) { return __uint_as_float(u & 0xFFFF0000u); }
__device__ inline unsigned f2bfbits(float f) {  // round-to-nearest-even
  unsigned x = __float_as_uint(f);
  return (x + 0x7FFFu + ((x >> 16) & 1u)) >> 16;
}
__device__ inline unsigned pack2(float a, float b) { return f2bfbits(a) | (f2bfbits(b) << 16); }

// ---------------- weight cast: W f32 [K][N] -> WThi/WTlo bf16 [N][K], 3 weights in one ----------------
__global__ void k_castW3(const float* __restrict__ W1, const float* __restrict__ W2,
                         const float* __restrict__ W3, unsigned short* __restrict__ WTh,
                         unsigned short* __restrict__ WTl) {
  int e = blockIdx.x * 256 + threadIdx.x;   // grid covers 3*FD*FD
  int which = e / (FD * FD);
  int r = e - which * (FD * FD);
  if (which >= 3) return;
  const float* W = which == 0 ? W1 : (which == 1 ? W2 : W3);
  int k = r >> 7, n = r & 127;
  float v = W[r];
  unsigned hb = f2bfbits(v);
  float hf = __uint_as_float(hb << 16);
  unsigned lb = f2bfbits(v - hf);
  WTh[which * FD * FD + n * FD + k] = (unsigned short)hb;
  WTl[which * FD * FD + n * FD + k] = (unsigned short)lb;
}

// ---------------- degree / CSR build ----------------

__global__ void k_init(float* psum) {
  int i = blockIdx.x * 256 + threadIdx.x;
  if (i < NG * FD) psum[i] = 0.f;
}

__global__ void k_count(const int* __restrict__ col, int* __restrict__ counts) {
  int e = blockIdx.x * 256 + threadIdx.x;
  if (e < NE) atomicAdd(&counts[col[e]], 1);
}

__global__ void k_dinv(const int* __restrict__ counts, float* __restrict__ dinv) {
  int n = blockIdx.x * 256 + threadIdx.x;
  if (n < NN) dinv[n] = rsqrtf((float)counts[n] + 1.0f);
}

// 3-phase scan over PADDED counts: ceil(deg/4)*4 per node
__global__ void k_bsum(const int* __restrict__ counts, int* __restrict__ bsum) {
  __shared__ int wsm[16];
  int b = blockIdx.x, t = threadIdx.x;
  int i = b * 1024 + t;
  int x = (i < NN) ? ((counts[i] + 3) & ~3) : 0;
#pragma unroll
  for (int d = 32; d; d >>= 1) x += __shfl_down(x, d);
  if ((t & 63) == 0) wsm[t >> 6] = x;
  __syncthreads();
  if (t < 16) {
    int s = wsm[t];
#pragma unroll
    for (int d = 8; d; d >>= 1) s += __shfl_down(s, d);
    if (t == 0) bsum[b] = s;
  }
}

__global__ void k_bscan(const int* __restrict__ bsum, int* __restrict__ eb) {
  __shared__ int w0;
  int t = threadIdx.x;  // 128
  int x = (t < NB) ? bsum[t] : 0;
  int lane = t & 63;
  int inc = x;
#pragma unroll
  for (int d = 1; d < 64; d <<= 1) { int y = __shfl_up(inc, d); if (lane >= d) inc += y; }
  if (t == 63) w0 = inc;
  __syncthreads();
  int off = (t >= 64) ? w0 : 0;
  if (t < NB) eb[t] = off + inc - x;  // exclusive
}

__global__ void k_scan2(const int* __restrict__ counts, const int* __restrict__ eb,
                        int* __restrict__ indptr) {
  __shared__ int wsm[16];
  int b = blockIdx.x, t = threadIdx.x;
  int i = b * 1024 + t;
  int x = (i < NN) ? ((counts[i] + 3) & ~3) : 0;
  int lane = t & 63, wid = t >> 6;
  int inc = x;
#pragma unroll
  for (int d = 1; d < 64; d <<= 1) { int y = __shfl_up(inc, d); if (lane >= d) inc += y; }
  if (lane == 63) wsm[wid] = inc;
  __syncthreads();
  if (wid == 0) {
    int s = (lane < 16) ? wsm[lane] : 0;
#pragma unroll
    for (int d = 1; d < 16; d <<= 1) { int y = __shfl_up(s, d); if (lane >= d) s += y; }
    if (lane < 16) wsm[lane] = s;
  }
  __syncthreads();
  int woff = wid ? wsm[wid - 1] : 0;
  if (i < NN) indptr[i + 1] = eb[b] + woff + inc;
  if (i == 0) indptr[0] = 0;
}

// combined edge record: {src, nrm}; pad slots stay {0, 0.0f} from memset (exact no-ops)
__global__ void k_fill(const int* __restrict__ row, const int* __restrict__ col,
                       const int* __restrict__ indptr, int* __restrict__ cursor,
                       const float* __restrict__ dinv, uint2* __restrict__ edges) {
  int e = blockIdx.x * 256 + threadIdx.x;
  if (e >= NE) return;
  int c = col[e], r = row[e];
  int p = indptr[c] + atomicAdd(&cursor[c], 1);
  edges[p] = make_uint2((unsigned)r, __float_as_uint(dinv[r] * dinv[c]));
}

// batch is sorted: ranges by boundary detection
__global__ void k_ranges(const int* __restrict__ batch, int* __restrict__ starts,
                         int* __restrict__ ends) {
  int n = blockIdx.x * 256 + threadIdx.x;
  if (n >= NN) return;
  int g = batch[n];
  if (n == 0) {
    starts[g] = 0;
    for (int q = 0; q < g; ++q) { starts[q] = 0; ends[q] = 0; }
  } else {
    int gp = batch[n - 1];
    if (gp != g) {
      ends[gp] = n;
      starts[g] = n;
      for (int q = gp + 1; q < g; ++q) { starts[q] = n; ends[q] = n; }
    }
  }
  if (n == NN - 1) {
    ends[g] = NN;
    for (int q = g + 1; q < NG; ++q) { starts[q] = NN; ends[q] = NN; }
  }
}

// ---------------- MFMA GEMM: Hb[M,128] = A[M,128] @ (WThi+WTlo)^T ----------------
template <int F32A>
__global__ __launch_bounds__(256) void k_gemm(const void* __restrict__ Aab,
                                              const unsigned short* __restrict__ WThi,
                                              const unsigned short* __restrict__ WTlo,
                                              unsigned short* __restrict__ Hb, int M) {
  __shared__ unsigned short wt[128][136];
  int t = threadIdx.x, lane = t & 63, w = t >> 6;
  int rowBase = blockIdx.x * 128 + w * 32;
  int r16 = lane & 15, kg = lane >> 4;

  f4v acc[2][8];
#pragma unroll
  for (int rt = 0; rt < 2; ++rt)
#pragma unroll
    for (int n = 0; n < 8; ++n) acc[rt][n] = (f4v){0.f, 0.f, 0.f, 0.f};

  s8v afr[2][4];
#pragma unroll
  for (int rt = 0; rt < 2; ++rt) {
    int ar = rowBase + rt * 16 + r16;
    if (ar > M - 1) ar = M - 1;
    if (F32A) {
      const float* ap = (const float*)Aab + (size_t)ar * FD + kg * 8;
#pragma unroll
      for (int c = 0; c < 4; ++c) {
        float4 p0 = *(const float4*)(ap + c * 32);
        float4 p1 = *(const float4*)(ap + c * 32 + 4);
        s8v f;
        f[0] = (short)f2bfbits(p0.x); f[1] = (short)f2bfbits(p0.y);
        f[2] = (short)f2bfbits(p0.z); f[3] = (short)f2bfbits(p0.w);
        f[4] = (short)f2bfbits(p1.x); f[5] = (short)f2bfbits(p1.y);
        f[6] = (short)f2bfbits(p1.z); f[7] = (short)f2bfbits(p1.w);
        afr[rt][c] = f;
      }
    } else {
      const unsigned short* ap = (const unsigned short*)Aab + (size_t)ar * FD + kg * 8;
#pragma unroll
      for (int c = 0; c < 4; ++c) afr[rt][c] = *(const s8v*)(ap + c * 32);
    }
  }

  for (int pass = 0; pass < 2; ++pass) {
    const unsigned short* Wg = pass ? WTlo : WThi;
    {
      int n = t >> 1, koff = (t & 1) * 64;
      const unsigned short* src = Wg + n * FD + koff;
#pragma unroll
      for (int j = 0; j < 8; ++j)
        *(s8v*)&wt[n][koff + j * 8] = *(const s8v*)(src + j * 8);
    }
    __syncthreads();
#pragma unroll
    for (int n = 0; n < 8; ++n) {
#pragma unroll
      for (int c = 0; c < 4; ++c) {
        s8v bfr = *(const s8v*)&wt[n * 16 + r16][c * 32 + kg * 8];
        acc[0][n] = __builtin_amdgcn_mfma_f32_16x16x32_bf16(afr[0][c], bfr, acc[0][n], 0, 0, 0);
        acc[1][n] = __builtin_amdgcn_mfma_f32_16x16x32_bf16(afr[1][c], bfr, acc[1][n], 0, 0, 0);
      }
    }
    __syncthreads();
  }

#pragma unroll
  for (int rt = 0; rt < 2; ++rt)
#pragma unroll
    for (int j = 0; j < 4; ++j) {
      int r = rowBase + rt * 16 + kg * 4 + j;
      if (r < M) {
#pragma unroll
        for (int n = 0; n < 8; ++n)
          Hb[(size_t)r * FD + n * 16 + r16] = (unsigned short)f2bfbits(acc[rt][n][j]);
      }
    }
}

// ---------------- aggregation: 2 nodes per wave (32-lane halves), uint2 lanes ----------------
// CSR segments are padded to multiples of 4 -> single branch-free 4-unrolled loop.
__global__ __launch_bounds__(256) void k_agg(const uint2* __restrict__ H2,
                                             const int* __restrict__ indptr,
                                             const uint2* __restrict__ edges,
                                             const float* __restrict__ dinv,
                                             const float* __restrict__ bias,
                                             uint2* __restrict__ out2, int relu) {
  int wid = (blockIdx.x * 256 + threadIdx.x) >> 6;  // global wave id
  int hl = threadIdx.x & 31;                        // lane within half
  int n = wid * 2 + ((threadIdx.x >> 5) & 1);       // node of this half
  if (n >= NN) return;
  float dv = dinv[n];
  float s2 = dv * dv;
  uint2 u = H2[(size_t)n * 32 + hl];
  float a0 = s2 * bflo(u.x), a1 = s2 * bfhi(u.x);
  float a2 = s2 * bflo(u.y), a3 = s2 * bfhi(u.y);
  int e0 = indptr[n], e1 = indptr[n + 1];  // e1-e0 is a multiple of 4
  for (int e = e0; e < e1; e += 4) {
    uint2 q0 = edges[e], q1 = edges[e + 1], q2 = edges[e + 2], q3 = edges[e + 3];
    uint2 v0 = H2[(size_t)q0.x * 32 + hl];
    uint2 v1 = H2[(size_t)q1.x * 32 + hl];
    uint2 v2 = H2[(size_t)q2.x * 32 + hl];
    uint2 v3 = H2[(size_t)q3.x * 32 + hl];
    float w0 = __uint_as_float(q0.y), w1 = __uint_as_float(q1.y);
    float w2 = __uint_as_float(q2.y), w3 = __uint_as_float(q3.y);
    a0 += w0 * bflo(v0.x); a1 += w0 * bfhi(v0.x); a2 += w0 * bflo(v0.y); a3 += w0 * bfhi(v0.y);
    a0 += w1 * bflo(v1.x); a1 += w1 * bfhi(v1.x); a2 += w1 * bflo(v1.y); a3 += w1 * bfhi(v1.y);
    a0 += w2 * bflo(v2.x); a1 += w2 * bfhi(v2.x); a2 += w2 * bflo(v2.y); a3 += w2 * bfhi(v2.y);
    a0 += w3 * bflo(v3.x); a1 += w3 * bfhi(v3.x); a2 += w3 * bflo(v3.y); a3 += w3 * bfhi(v3.y);
  }
  a0 += bias[hl * 4];
  a1 += bias[hl * 4 + 1];
  a2 += bias[hl * 4 + 2];
  a3 += bias[hl * 4 + 3];
  if (relu) {
    a0 = fmaxf(a0, 0.f); a1 = fmaxf(a1, 0.f);
    a2 = fmaxf(a2, 0.f); a3 = fmaxf(a3, 0.f);
  }
  out2[(size_t)n * 32 + hl] = make_uint2(pack2(a0, a1), pack2(a2, a3));
}

// ---------------- mean pool: wave per 64-node chunk, lanes cover row as bf16x2 ----------------
#define PW 64  // nodes per wave
__global__ __launch_bounds__(256) void k_pool(const unsigned* __restrict__ H2,
                                              const int* __restrict__ batch,
                                              float* __restrict__ psum) {
  int wgl = (blockIdx.x * 256 + threadIdx.x) >> 6;  // global wave id
  int lane = threadIdx.x & 63;
  int n0 = wgl * PW;
  if (n0 >= NN) return;
  int n1 = n0 + PW; if (n1 > NN) n1 = NN;
  int g0 = batch[n0], g1 = batch[n1 - 1];
  float a0 = 0.f, a1 = 0.f;
  if (g0 == g1) {
    int n = n0;
    for (; n + 3 < n1; n += 4) {
      unsigned v0 = H2[(size_t)(n + 0) * 64 + lane];
      unsigned v1 = H2[(size_t)(n + 1) * 64 + lane];
      unsigned v2 = H2[(size_t)(n + 2) * 64 + lane];
      unsigned v3 = H2[(size_t)(n + 3) * 64 + lane];
      a0 += bflo(v0) + bflo(v1) + bflo(v2) + bflo(v3);
      a1 += bfhi(v0) + bfhi(v1) + bfhi(v2) + bfhi(v3);
    }
    for (; n < n1; ++n) {
      unsigned v = H2[(size_t)n * 64 + lane];
      a0 += bflo(v); a1 += bfhi(v);
    }
    atomicAdd(&psum[g0 * FD + lane * 2], a0);
    atomicAdd(&psum[g0 * FD + lane * 2 + 1], a1);
  } else {
    int g = g0;
    for (int n = n0; n < n1; ++n) {
      int gn = batch[n];
      if (gn != g) {
        atomicAdd(&psum[g * FD + lane * 2], a0);
        atomicAdd(&psum[g * FD + lane * 2 + 1], a1);
        a0 = 0.f; a1 = 0.f; g = gn;
      }
      unsigned v = H2[(size_t)n * 64 + lane];
      a0 += bflo(v); a1 += bfhi(v);
    }
    atomicAdd(&psum[g * FD + lane * 2], a0);
    atomicAdd(&psum[g * FD + lane * 2 + 1], a1);
  }
}

__global__ void k_head(const float* __restrict__ psum, const int* __restrict__ starts,
                       const int* __restrict__ ends, const float* __restrict__ Wl,
                       const float* __restrict__ bl, float* __restrict__ out) {
  int t = threadIdx.x;  // 128 = 64 graphs x 2 classes
  int g = t >> 1, c = t & 1;
  int cnt = ends[g] - starts[g];
  if (cnt < 0) cnt = 0;
  float inv = 1.f / (float)(cnt > 0 ? cnt : 1);
  float acc = 0.f;
  for (int k = 0; k < FD; ++k) acc += psum[g * FD + k] * Wl[k * 2 + c];
  out[g * 2 + c] = acc * inv + bl[c];
}

// ---------------- host ----------------

extern "C" void kernel_launch(void* const* d_in, const int* in_sizes, int n_in,
                              void* d_out, int out_size, void* d_ws, size_t ws_size,
                              hipStream_t stream) {
  const float* x  = (const float*)d_in[0];
  const int* ei   = (const int*)d_in[1];
  const int* bat  = (const int*)d_in[2];
  const float* W1 = (const float*)d_in[3];
  const float* b1 = (const float*)d_in[4];
  const float* W2 = (const float*)d_in[5];
  const float* b2 = (const float*)d_in[6];
  const float* W3 = (const float*)d_in[7];
  const float* b3 = (const float*)d_in[8];
  const float* Wl = (const float*)d_in[9];
  const float* bl = (const float*)d_in[10];
  float* out = (float*)d_out;

  char* ws = (char*)d_ws;
  size_t off = 0;
  auto alloc = [&](size_t bytes) {
    void* p = ws + off;
    off += (bytes + 255) & ~(size_t)255;
    return p;
  };
  int* counts  = (int*)alloc(NN * 4);
  int* cursor  = (int*)alloc(NN * 4);
  int* indptr  = (int*)alloc((NN + 1) * 4);
  float* dinv  = (float*)alloc(NN * 4);
  int* bsum    = (int*)alloc(NB * 4);
  int* eb      = (int*)alloc(NB * 4);
  int* starts  = (int*)alloc(NG * 4);
  int* ends    = (int*)alloc(NG * 4);
  float* psum  = (float*)alloc(NG * FD * 4);
  uint2* edges = (uint2*)alloc((size_t)EPAD * 8);
  unsigned short* Hb   = (unsigned short*)alloc((size_t)NN * FD * 2);
  unsigned short* Abuf = (unsigned short*)alloc((size_t)NN * FD * 2);
  unsigned short* WTh  = (unsigned short*)alloc(3 * FD * FD * 2);
  unsigned short* WTl  = (unsigned short*)alloc(3 * FD * FD * 2);

  const int* row = ei;
  const int* col = ei + NE;

  hipMemsetAsync(counts, 0, NN * 4, stream);
  hipMemsetAsync(cursor, 0, NN * 4, stream);
  hipMemsetAsync(edges, 0, (size_t)EPAD * 8, stream);
  k_init<<<32, 256, 0, stream>>>(psum);
  k_castW3<<<(3 * FD * FD + 255) / 256, 256, 0, stream>>>(W1, W2, W3, WTh, WTl);
  k_ranges<<<(NN + 255) / 256, 256, 0, stream>>>(bat, starts, ends);
  k_count<<<(NE + 255) / 256, 256, 0, stream>>>(col, counts);
  k_dinv<<<(NN + 255) / 256, 256, 0, stream>>>(counts, dinv);
  k_bsum<<<NB, 1024, 0, stream>>>(counts, bsum);
  k_bscan<<<1, 128, 0, stream>>>(bsum, eb);
  k_scan2<<<NB, 1024, 0, stream>>>(counts, eb, indptr);
  k_fill<<<(NE + 255) / 256, 256, 0, stream>>>(row, col, indptr, cursor, dinv, edges);

  int gemmGrid = (NN + 127) / 128;
  int aggGrid = (NN + 7) / 8;   // 8 nodes per block (2 per wave x 4 waves)
  int poolGrid = ((NN + PW - 1) / PW * 64 + 255) / 256;

  k_gemm<1><<<gemmGrid, 256, 0, stream>>>(x, WTh, WTl, Hb, NN);
  k_agg<<<aggGrid, 256, 0, stream>>>((const uint2*)Hb, indptr, edges, dinv, b1,
                                     (uint2*)Abuf, 1);
  k_gemm<0><<<gemmGrid, 256, 0, stream>>>(Abuf, WTh + FD * FD, WTl + FD * FD, Hb, NN);
  k_agg<<<aggGrid, 256, 0, stream>>>((const uint2*)Hb, indptr, edges, dinv, b2,
                                     (uint2*)Abuf, 1);
  k_gemm<0><<<gemmGrid, 256, 0, stream>>>(Abuf, WTh + 2 * FD * FD, WTl + 2 * FD * FD, Hb, NN);
  k_agg<<<aggGrid, 256, 0, stream>>>((const uint2*)Hb, indptr, edges, dinv, b3,
                                     (uint2*)Abuf, 0);

  k_pool<<<poolGrid, 256, 0, stream>>>((const unsigned*)Abuf, bat, psum);
  k_head<<<1, 128, 0, stream>>>(psum, starts, ends, Wl, bl, out);
}